// Round 10
// baseline (205.862 us; speedup 1.0000x reference)
//
#include <hip/hip_runtime.h>
#include <hip/hip_bf16.h>

// GCN 2-layer forward. Pipeline: memset(deg) -> init+degHist -> [gemm1 || binA
// merged] -> binB -> agg -> gather2. gemm1 scales rows by rsqrt(1+deg[row]) on the
// fly (deg from early histogram), so h1s is PRE-SCALED and agg is the r7 champion
// (42.4us, no per-edge dinv loads). Agg at ~2.6TB/s random-fill wall, FETCH ~107MB.

#define D1 128
#define BSH 8                 // 256 nodes per bucket
#define BSZ (1 << BSH)
#define NBMAX 1024            // max buckets supported
#define CHA 2048              // edges per block in pass A
#define BMM 128               // gemm1 rows per block

typedef __attribute__((ext_vector_type(8))) short short8;
typedef __attribute__((ext_vector_type(4))) float floatx4;

__device__ __forceinline__ unsigned short f2bf(float f) {
    unsigned u = __float_as_uint(f);
    u += 0x7fff + ((u >> 16) & 1);         // RNE to bf16
    return (unsigned short)(u >> 16);
}
__device__ __forceinline__ float bflo(unsigned u) { return __uint_as_float(u << 16); }
__device__ __forceinline__ float bfhi(unsigned u) { return __uint_as_float(u & 0xffff0000u); }
__device__ __forceinline__ int clampN(int s, int N) {
    return (int)min((unsigned)s, (unsigned)N);   // catches negatives too
}

// ------- init: zero cursors, pad rows, W1 -> W1^T bf16, dst-degree histogram -------
// deg[] must be zeroed (hipMemsetAsync) before this kernel.
__global__ __launch_bounds__(256) void k_init(
    const float* __restrict__ W1, unsigned short* __restrict__ W1t,
    int* __restrict__ bcur, unsigned short* __restrict__ h1s,
    float* __restrict__ h2s, const int* __restrict__ dst, int* __restrict__ deg,
    int N, int E) {
    int i = blockIdx.x * 256 + threadIdx.x;
    if (i < NBMAX) bcur[i] = 0;
    if (i < D1) h1s[(size_t)N * D1 + i] = 0;         // zero pad row for gathers
    if (i < 2)  h2s[(size_t)N * 2 + i] = 0.f;        // zero pad row for gather2
    if (i < D1 * D1) {
        int c = i >> 7, k = i & 127;
        W1t[c * D1 + k] = f2bf(W1[k * D1 + c]);
    }
    for (int e = i; e < E; e += gridDim.x * 256)     // in-degree histogram
        atomicAdd(&deg[dst[e]], 1);
}

// ---------------- merged: gemm1 (x@W1 * rsqrt(1+deg) -> bf16 h1s) || binA ----------
// Block-split, interleaved even/odd so latency-bound binA overlaps BW-bound gemm1.
__global__ __launch_bounds__(512) void k_gemm1_binA(
    const float* __restrict__ x, const unsigned short* __restrict__ W1t,
    const int* __restrict__ deg, unsigned short* __restrict__ h1s,
    const int* __restrict__ src, const int* __restrict__ dst,
    int* __restrict__ bcur, unsigned* __restrict__ packed,
    int N, int E, int nbuck, int CAP, int GA, int GG)
{
    __shared__ __align__(16) char smem[2 * BMM * 136 * 2];   // 69632 B union

    const int b = blockIdx.x;
    const int m2 = 2 * min(GA, GG);
    bool isA;
    int bid;
    if (b < m2)            { isA = (b & 1); bid = b >> 1; }
    else if (GA <= GG)     { isA = false;   bid = min(GA, GG) + (b - m2); }
    else                   { isA = true;    bid = min(GA, GG) + (b - m2); }

    if (isA) {
        // ---- binA part: bucket edges into slack regions ----
        int* hist = (int*)smem;
        int* cur  = hist + NBMAX;
        const int t = threadIdx.x;
        const int e0 = bid * CHA;
        const int e1 = min(e0 + CHA, E);

        for (int i = t; i < nbuck; i += 512) hist[i] = 0;
        __syncthreads();
        for (int i = e0 + t; i < e1; i += 512)
            atomicAdd(&hist[dst[i] >> BSH], 1);
        __syncthreads();
        for (int i = t; i < nbuck; i += 512)
            cur[i] = (hist[i] > 0) ? atomicAdd(&bcur[i], hist[i]) : 0;
        __syncthreads();
        for (int i = e0 + t; i < e1; i += 512) {
            int d = dst[i];
            int bk = d >> BSH;
            int pos = atomicAdd(&cur[bk], 1);
            if (pos < CAP)
                packed[(size_t)bk * CAP + pos] =
                    ((unsigned)src[i] << BSH) | (unsigned)(d & (BSZ - 1));
        }
        return;
    }

    // ---- gemm1 part: h1s = bf16((x @ W1) * rsqrt(1+deg[row])) ----
    unsigned short (*Xs)[136] = (unsigned short(*)[136])smem;
    unsigned short (*Ws)[136] = (unsigned short(*)[136])(smem + BMM * 136 * 2);

    const int t = threadIdx.x;
    const int row0 = bid * BMM;

#pragma unroll
    for (int i = 0; i < 4; ++i) {
        int idx = t + 512 * i;                // 2048 = 128 rows x 16 chunks
        int r = idx >> 4, c8 = idx & 15;
        short8 v = ((const short8*)W1t)[r * 16 + c8];
        *(short8*)&Ws[r][c8 * 8] = v;
    }
#pragma unroll
    for (int i = 0; i < 4; ++i) {
        int idx = t + 512 * i;
        int r = idx >> 4, c8 = idx & 15;
        int row = row0 + r;
        short8 v8 = (short8)0;
        if (row < N) {
            const float* p = x + (size_t)row * D1 + c8 * 8;
            float4 f0 = *(const float4*)p;
            float4 f1 = *(const float4*)(p + 4);
            v8[0] = (short)f2bf(f0.x); v8[1] = (short)f2bf(f0.y);
            v8[2] = (short)f2bf(f0.z); v8[3] = (short)f2bf(f0.w);
            v8[4] = (short)f2bf(f1.x); v8[5] = (short)f2bf(f1.y);
            v8[6] = (short)f2bf(f1.z); v8[7] = (short)f2bf(f1.w);
        }
        *(short8*)&Xs[r][c8 * 8] = v8;
    }
    __syncthreads();

    const int w = t >> 6;                     // 8 waves: rows 16w..16w+15
    const int l = t & 63;
    const int m = l & 15;
    const int q = l >> 4;

    floatx4 acc[8];
#pragma unroll
    for (int c = 0; c < 8; ++c) acc[c] = (floatx4)0.0f;

#pragma unroll
    for (int ks = 0; ks < 4; ++ks) {
        short8 a = *(const short8*)&Xs[16 * w + m][ks * 32 + q * 8];
#pragma unroll
        for (int c = 0; c < 8; ++c) {
            short8 bb = *(const short8*)&Ws[c * 16 + m][ks * 32 + q * 8];
            acc[c] = __builtin_amdgcn_mfma_f32_16x16x32_bf16(a, bb, acc[c], 0, 0, 0);
        }
    }

    __syncthreads();   // everyone done reading Xs/Ws

#pragma unroll
    for (int r = 0; r < 4; ++r) {
        int rt = 16 * w + q * 4 + r;            // row in tile
        int row = row0 + rt;
        float di = (row < N) ? rsqrtf(1.0f + (float)deg[row]) : 0.f;
#pragma unroll
        for (int c = 0; c < 8; ++c)
            Xs[rt][c * 16 + m] = f2bf(acc[c][r] * di);
    }
    __syncthreads();

#pragma unroll
    for (int i = 0; i < 4; ++i) {
        int idx = t + 512 * i;
        int r = idx >> 4, c8 = idx & 15;
        int row = row0 + r;
        if (row < N)
            *(short8*)&h1s[(size_t)row * D1 + c8 * 8] = *(const short8*)&Xs[r][c8 * 8];
    }
}

// ---------------- pass B: per-bucket hist/scan (padded-to-4 degrees)/rp/dinv/esrc
//                  + DESCENDING-degree schedule (order); wave-shfl scans. ---------
__global__ __launch_bounds__(BSZ) void k_binB(
    const int* __restrict__ bcur, const unsigned* __restrict__ packed,
    int2* __restrict__ rp, float* __restrict__ dinv,
    int* __restrict__ esrc, int* __restrict__ order, int N, int CAP)
{
    __shared__ int lh[BSZ];
    __shared__ int lcur[BSZ];
    __shared__ int wsum[BSZ / 64];
    __shared__ int dbin[64];
    __shared__ int dcur[64];

    const int t = threadIdx.x;
    const int s = blockIdx.x << BSH;
    const int n = min(BSZ, N - s);
    const int base = blockIdx.x * CAP;
    const int cnt = min(bcur[blockIdx.x], CAP);

    lh[t] = 0;
    if (t < 64) dbin[t] = 0;
    __syncthreads();
    for (int i = t; i < cnt; i += BSZ)
        atomicAdd(&lh[packed[base + i] & (BSZ - 1)], 1);
    __syncthreads();

    const int deg = lh[t];                   // true degree (in-bucket)
    const int pdeg = (deg + 3) & ~3;         // padded to x4 for int4 index loads

    // exclusive scan of pdeg via wave shfl scans
    int inc = pdeg;
#pragma unroll
    for (int off = 1; off < 64; off <<= 1) {
        int u = __shfl_up(inc, off);
        if ((t & 63) >= off) inc += u;
    }
    if ((t & 63) == 63) wsum[t >> 6] = inc;
    __syncthreads();
    if (t < BSZ / 64) {
        int w = wsum[t];
#pragma unroll
        for (int off = 1; off < BSZ / 64; off <<= 1) {
            int u = __shfl_up(w, off, BSZ / 64);
            if ((t & (BSZ / 64 - 1)) >= off) w += u;
        }
        wsum[t] = w;                               // inclusive wave sums
    }
    __syncthreads();
    int excl = ((t >> 6) ? wsum[(t >> 6) - 1] : 0) + inc - pdeg;

    if (t < n) {
        rp[s + t] = make_int2(base + excl, deg);
        dinv[s + t] = rsqrtf(1.0f + (float)deg);
        atomicAdd(&dbin[63 - min(deg, 63)], 1);    // reversed key -> descending
        for (int k = deg; k < pdeg; ++k) {         // pad slots -> zero-row index
            int p = excl + k;
            if (p < CAP) esrc[base + p] = N;       // clamp (no-op at this fill factor)
        }
    }
    lcur[t] = excl;
    __syncthreads();

    for (int i = t; i < cnt; i += BSZ) {
        unsigned p = packed[base + i];
        int ld = (int)(p & (BSZ - 1));
        int pos = atomicAdd(&lcur[ld], 1);
        if (pos < CAP) esrc[base + pos] = (int)(p >> BSH);
    }

    __syncthreads();
    if (t < 64) {                                  // exactly wave 0
        int dv = dbin[t];
        int dinc = dv;
#pragma unroll
        for (int off = 1; off < 64; off <<= 1) {
            int u = __shfl_up(dinc, off);
            if (t >= off) dinc += u;
        }
        dcur[t] = dinc - dv;
    }
    __syncthreads();
    if (t < n) {
        int b = 63 - min(deg, 63);
        int pos = atomicAdd(&dcur[b], 1);
        order[s + pos] = s + t;
    }
}

#define ACC8(A, v) \
    A[0] += bflo(v.x); A[1] += bfhi(v.x); \
    A[2] += bflo(v.y); A[3] += bfhi(v.y); \
    A[4] += bflo(v.z); A[5] += bfhi(v.z); \
    A[6] += bflo(v.w); A[7] += bfhi(v.w);

// ---------------- fused: agg(layer1) + relu + bias + GEMM2  [r7 champion @42.4us] --
__global__ __launch_bounds__(256) void k_agg1_gemm2(
    const int2* __restrict__ rp, const int* __restrict__ esrc,
    const int* __restrict__ order,
    const float* __restrict__ dinv, const unsigned short* __restrict__ h1s,
    const float* __restrict__ b1, const float* __restrict__ W2,
    float* __restrict__ h2s, int N)
{
    int gid = blockIdx.x * 256 + threadIdx.x;
    int grp = gid >> 4;
    if (grp >= N) return;
    int node = order[grp];
    int lane = gid & 15;

    const uint4* h1v = (const uint4*)h1s;   // 16 uint4 per row
    const int4*  ev  = (const int4*)esrc;   // per-node regions are x4-aligned

    uint4 u = h1v[(size_t)node * 16 + lane];
    float accA[8], accB[8];
    accA[0] = bflo(u.x); accA[1] = bfhi(u.x);
    accA[2] = bflo(u.y); accA[3] = bfhi(u.y);
    accA[4] = bflo(u.z); accA[5] = bfhi(u.z);
    accA[6] = bflo(u.w); accA[7] = bfhi(u.w);
#pragma unroll
    for (int j = 0; j < 8; ++j) accB[j] = 0.f;

    int2 r = rp[node];
    int beg = r.x;
    int end4 = beg + ((r.y + 3) & ~3);

    for (int e = beg; e < end4; e += 8) {
        int q = e >> 2;
        int4 i0 = ev[q];                     // always valid (real or N-pad)
        int4 i1 = ev[q + 1];                 // in-bounds read; masked if past end4
        bool c1 = (e + 4) < end4;
        int s0 = clampN(i0.x, N), s1 = clampN(i0.y, N);
        int s2 = clampN(i0.z, N), s3 = clampN(i0.w, N);
        int s4 = c1 ? clampN(i1.x, N) : N, s5 = c1 ? clampN(i1.y, N) : N;
        int s6 = c1 ? clampN(i1.z, N) : N, s7 = c1 ? clampN(i1.w, N) : N;
        uint4 v0 = h1v[(size_t)s0 * 16 + lane];
        uint4 v1 = h1v[(size_t)s1 * 16 + lane];
        uint4 v2 = h1v[(size_t)s2 * 16 + lane];
        uint4 v3 = h1v[(size_t)s3 * 16 + lane];
        uint4 v4 = h1v[(size_t)s4 * 16 + lane];
        uint4 v5 = h1v[(size_t)s5 * 16 + lane];
        uint4 v6 = h1v[(size_t)s6 * 16 + lane];
        uint4 v7 = h1v[(size_t)s7 * 16 + lane];
        ACC8(accA, v0) ACC8(accB, v1) ACC8(accA, v2) ACC8(accB, v3)
        ACC8(accA, v4) ACC8(accB, v5) ACC8(accA, v6) ACC8(accB, v7)
    }

    float di = dinv[node];
    const float4* b1v = (const float4*)b1;
    float4 bbA = b1v[lane * 2 + 0];
    float4 bbB = b1v[lane * 2 + 1];
    float a[8];
    a[0] = fmaxf((accA[0] + accB[0]) * di + bbA.x, 0.f);
    a[1] = fmaxf((accA[1] + accB[1]) * di + bbA.y, 0.f);
    a[2] = fmaxf((accA[2] + accB[2]) * di + bbA.z, 0.f);
    a[3] = fmaxf((accA[3] + accB[3]) * di + bbA.w, 0.f);
    a[4] = fmaxf((accA[4] + accB[4]) * di + bbB.x, 0.f);
    a[5] = fmaxf((accA[5] + accB[5]) * di + bbB.y, 0.f);
    a[6] = fmaxf((accA[6] + accB[6]) * di + bbB.z, 0.f);
    a[7] = fmaxf((accA[7] + accB[7]) * di + bbB.w, 0.f);

    const float4* W2v = (const float4*)W2;
    float p0 = 0.f, p1 = 0.f;
#pragma unroll
    for (int j2 = 0; j2 < 4; ++j2) {
        float4 wv = W2v[lane * 4 + j2];
        p0 += a[j2 * 2] * wv.x + a[j2 * 2 + 1] * wv.z;
        p1 += a[j2 * 2] * wv.y + a[j2 * 2 + 1] * wv.w;
    }

#pragma unroll
    for (int off = 8; off > 0; off >>= 1) {
        p0 += __shfl_xor(p0, off);
        p1 += __shfl_xor(p1, off);
    }
    if (lane == 0) {
        h2s[(size_t)node * 2 + 0] = p0 * di;   // store h2*dinv
        h2s[(size_t)node * 2 + 1] = p1 * di;
    }
}

// ---------------- gather layer 2: out = dinv_i*(h2s_i + sum h2s_src) + b2 -------
__global__ void k_gather2(const int2* __restrict__ rp, const int* __restrict__ esrc,
                          const float* __restrict__ h2s, const float* __restrict__ dinv,
                          const float* __restrict__ b2, float* __restrict__ out, int N)
{
    int i = blockIdx.x * 256 + threadIdx.x;
    if (i >= N) return;
    const float2* h2v = (const float2*)h2s;
    const int4* ev = (const int4*)esrc;
    float2 h = h2v[i];
    float o0a = h.x, o1a = h.y;
    float o0b = 0.f, o1b = 0.f;
    int2 r = rp[i];
    int beg = r.x;
    int end4 = beg + ((r.y + 3) & ~3);
    for (int e = beg; e < end4; e += 16) {
        int q = e >> 2;
        int4 i0 = ev[q];
        int4 i1 = ev[q + 1];
        int4 i2 = ev[q + 2];
        int4 i3 = ev[q + 3];
        bool c1 = (e + 4) < end4, c2 = (e + 8) < end4, c3 = (e + 12) < end4;
        int s0 = clampN(i0.x, N), s1 = clampN(i0.y, N);
        int s2 = clampN(i0.z, N), s3 = clampN(i0.w, N);
        int s4 = c1 ? clampN(i1.x, N) : N, s5 = c1 ? clampN(i1.y, N) : N;
        int s6 = c1 ? clampN(i1.z, N) : N, s7 = c1 ? clampN(i1.w, N) : N;
        int s8 = c2 ? clampN(i2.x, N) : N, s9 = c2 ? clampN(i2.y, N) : N;
        int sa = c2 ? clampN(i2.z, N) : N, sb = c2 ? clampN(i2.w, N) : N;
        int sc = c3 ? clampN(i3.x, N) : N, sd = c3 ? clampN(i3.y, N) : N;
        int se = c3 ? clampN(i3.z, N) : N, sf = c3 ? clampN(i3.w, N) : N;
        float2 v0 = h2v[s0], v1 = h2v[s1], v2 = h2v[s2], v3 = h2v[s3];
        float2 v4 = h2v[s4], v5 = h2v[s5], v6 = h2v[s6], v7 = h2v[s7];
        float2 v8 = h2v[s8], v9 = h2v[s9], va = h2v[sa], vb = h2v[sb];
        float2 vc = h2v[sc], vd = h2v[sd], ve = h2v[se], vf = h2v[sf];
        o0a += v0.x + v2.x + v4.x + v6.x + v8.x + va.x + vc.x + ve.x;
        o1a += v0.y + v2.y + v4.y + v6.y + v8.y + va.y + vc.y + ve.y;
        o0b += v1.x + v3.x + v5.x + v7.x + v9.x + vb.x + vd.x + vf.x;
        o1b += v1.y + v3.y + v5.y + v7.y + v9.y + vb.y + vd.y + vf.y;
    }
    float di = dinv[i];
    ((float2*)out)[i] = make_float2((o0a + o0b) * di + b2[0], (o1a + o1b) * di + b2[1]);
}

extern "C" void kernel_launch(void* const* d_in, const int* in_sizes, int n_in,
                              void* d_out, int out_size, void* d_ws, size_t ws_size,
                              hipStream_t stream)
{
    const float* x  = (const float*)d_in[0];
    const int*   ei = (const int*)d_in[1];
    const float* W1 = (const float*)d_in[2];
    const float* b1 = (const float*)d_in[3];
    const float* W2 = (const float*)d_in[4];
    const float* b2 = (const float*)d_in[5];
    float* out = (float*)d_out;

    const int N = in_sizes[0] / D1;
    const int E = in_sizes[1] / 2;
    const int* src = ei;
    const int* dst = ei + E;

    const int nbuck = (N + BSZ - 1) >> BSH;
    const int avg = (E + nbuck - 1) / nbuck;
    // 2x mean bucket fill + room for per-node x4 padding (<= 3*BSZ), 64-aligned
    const int CAP = (2 * avg + 3 * BSZ + 63) & ~63;

    char* w = (char*)d_ws;
    auto alloc = [&](size_t bytes) -> char* {
        char* r = w;
        w += (bytes + 63) & ~(size_t)63;
        return r;
    };
    unsigned short* h1s = (unsigned short*)alloc((size_t)(N + 1) * D1 * 2); // +pad row
    unsigned short* W1t = (unsigned short*)alloc((size_t)D1 * D1 * 2);
    float* h2s    = (float*)alloc((size_t)(N + 1) * 2 * 4);                 // +pad row
    float* dinv   = (float*)alloc((size_t)(N + 1) * 4);
    int*   deg    = (int*)alloc((size_t)N * 4);
    int2*  rp     = (int2*)alloc((size_t)N * 8);
    int*   order  = (int*)alloc((size_t)N * 4);
    int*   bcur   = (int*)alloc(NBMAX * 4);
    unsigned* packed = (unsigned*)alloc((size_t)nbuck * CAP * 4);
    int*   esrc   = (int*)alloc(((size_t)nbuck * CAP + 256) * 4);           // +overread slack

    const int GA = (E + CHA - 1) / CHA;
    const int GG = (N + BMM - 1) / BMM;

    hipMemsetAsync(deg, 0, (size_t)N * 4, stream);
    k_init <<<GA, 256, 0, stream>>>(W1, W1t, bcur, h1s, h2s, dst, deg, N, E);
    k_gemm1_binA<<<GA + GG, 512, 0, stream>>>(x, W1t, deg, h1s, src, dst, bcur, packed,
                                              N, E, nbuck, CAP, GA, GG);
    k_binB <<<nbuck, BSZ, 0, stream>>>(bcur, packed, rp, dinv, esrc, order, N, CAP);

    k_agg1_gemm2<<<(N * 16 + 255) / 256, 256, 0, stream>>>(rp, esrc, order, dinv, h1s, b1, W2, h2s, N);

    k_gather2<<<(N + 255) / 256, 256, 0, stream>>>(rp, esrc, h2s, dinv, b2, out, N);
}

// Round 11
// 179.168 us; speedup vs baseline: 1.1490x; 1.1490x over previous
//
#include <hip/hip_runtime.h>
#include <hip/hip_bf16.h>

// GCN 2-layer forward. CHAMPION RESTORE (r9, measured 180.4us).
// 5-kernel pipeline: init -> [gemm1 || binA merged] -> binB -> agg -> gather2.
// h1s is UNSCALED bf16(x@W1); dinv[src] applied as per-edge FMA scalar in agg
// (breaks gemm1's false dep on binB, enabling the merge/overlap which measured
// ~11.6us of build-side savings). Agg at ~2.2-2.6TB/s random-fill wall; FETCH
// pinned ~107-110MB = compulsory 8-XCD L2-fill traffic of h1s (bf16 floor).

#define D1 128
#define BSH 8                 // 256 nodes per bucket
#define BSZ (1 << BSH)
#define NBMAX 1024            // max buckets supported
#define CHA 2048              // edges per block in pass A
#define BMM 128               // gemm1 rows per block

typedef __attribute__((ext_vector_type(8))) short short8;
typedef __attribute__((ext_vector_type(4))) float floatx4;

__device__ __forceinline__ unsigned short f2bf(float f) {
    unsigned u = __float_as_uint(f);
    u += 0x7fff + ((u >> 16) & 1);         // RNE to bf16
    return (unsigned short)(u >> 16);
}
__device__ __forceinline__ float bflo(unsigned u) { return __uint_as_float(u << 16); }
__device__ __forceinline__ float bfhi(unsigned u) { return __uint_as_float(u & 0xffff0000u); }
__device__ __forceinline__ int clampN(int s, int N) {
    return (int)min((unsigned)s, (unsigned)N);   // catches negatives too
}

// ---------------- init: zero bucket cursors, zero pad rows, W1 -> W1^T bf16 ---------
__global__ void k_init(const float* __restrict__ W1, unsigned short* __restrict__ W1t,
                       int* __restrict__ bcur, unsigned short* __restrict__ h1s,
                       float* __restrict__ h2s, float* __restrict__ dinv, int N) {
    int i = blockIdx.x * 256 + threadIdx.x;
    if (i < NBMAX) bcur[i] = 0;
    if (i < D1) h1s[(size_t)N * D1 + i] = 0;         // zero pad row for gathers
    if (i < 2)  h2s[(size_t)N * 2 + i] = 0.f;        // zero pad row for gather2
    if (i == 0) dinv[N] = 0.f;                       // pad slot for per-edge dinv FMA
    if (i < D1 * D1) {
        int c = i >> 7, k = i & 127;
        W1t[c * D1 + k] = f2bf(W1[k * D1 + c]);
    }
}

// ---------------- merged: gemm1 (x@W1 -> bf16 h1s, UNSCALED) || binA (bucket edges) -
// Block-split, interleaved even/odd so latency-bound binA overlaps BW-bound gemm1.
__global__ __launch_bounds__(512) void k_gemm1_binA(
    const float* __restrict__ x, const unsigned short* __restrict__ W1t,
    unsigned short* __restrict__ h1s,
    const int* __restrict__ src, const int* __restrict__ dst,
    int* __restrict__ bcur, unsigned* __restrict__ packed,
    int N, int E, int nbuck, int CAP, int GA, int GG)
{
    __shared__ __align__(16) char smem[2 * BMM * 136 * 2];   // 69632 B union

    const int b = blockIdx.x;
    const int m2 = 2 * min(GA, GG);
    bool isA;
    int bid;
    if (b < m2)            { isA = (b & 1); bid = b >> 1; }
    else if (GA <= GG)     { isA = false;   bid = min(GA, GG) + (b - m2); }
    else                   { isA = true;    bid = min(GA, GG) + (b - m2); }

    if (isA) {
        // ---- binA part: bucket edges into slack regions ----
        int* hist = (int*)smem;
        int* cur  = hist + NBMAX;
        const int t = threadIdx.x;
        const int e0 = bid * CHA;
        const int e1 = min(e0 + CHA, E);

        for (int i = t; i < nbuck; i += 512) hist[i] = 0;
        __syncthreads();
        for (int i = e0 + t; i < e1; i += 512)
            atomicAdd(&hist[dst[i] >> BSH], 1);
        __syncthreads();
        for (int i = t; i < nbuck; i += 512)
            cur[i] = (hist[i] > 0) ? atomicAdd(&bcur[i], hist[i]) : 0;
        __syncthreads();
        for (int i = e0 + t; i < e1; i += 512) {
            int d = dst[i];
            int bk = d >> BSH;
            int pos = atomicAdd(&cur[bk], 1);
            if (pos < CAP)
                packed[(size_t)bk * CAP + pos] =
                    ((unsigned)src[i] << BSH) | (unsigned)(d & (BSZ - 1));
        }
        return;
    }

    // ---- gemm1 part: h1s = bf16(x @ W1), no dinv scaling ----
    unsigned short (*Xs)[136] = (unsigned short(*)[136])smem;
    unsigned short (*Ws)[136] = (unsigned short(*)[136])(smem + BMM * 136 * 2);

    const int t = threadIdx.x;
    const int row0 = bid * BMM;

#pragma unroll
    for (int i = 0; i < 4; ++i) {
        int idx = t + 512 * i;                // 2048 = 128 rows x 16 chunks
        int r = idx >> 4, c8 = idx & 15;
        short8 v = ((const short8*)W1t)[r * 16 + c8];
        *(short8*)&Ws[r][c8 * 8] = v;
    }
#pragma unroll
    for (int i = 0; i < 4; ++i) {
        int idx = t + 512 * i;
        int r = idx >> 4, c8 = idx & 15;
        int row = row0 + r;
        short8 v8 = (short8)0;
        if (row < N) {
            const float* p = x + (size_t)row * D1 + c8 * 8;
            float4 f0 = *(const float4*)p;
            float4 f1 = *(const float4*)(p + 4);
            v8[0] = (short)f2bf(f0.x); v8[1] = (short)f2bf(f0.y);
            v8[2] = (short)f2bf(f0.z); v8[3] = (short)f2bf(f0.w);
            v8[4] = (short)f2bf(f1.x); v8[5] = (short)f2bf(f1.y);
            v8[6] = (short)f2bf(f1.z); v8[7] = (short)f2bf(f1.w);
        }
        *(short8*)&Xs[r][c8 * 8] = v8;
    }
    __syncthreads();

    const int w = t >> 6;                     // 8 waves: rows 16w..16w+15
    const int l = t & 63;
    const int m = l & 15;
    const int q = l >> 4;

    floatx4 acc[8];
#pragma unroll
    for (int c = 0; c < 8; ++c) acc[c] = (floatx4)0.0f;

#pragma unroll
    for (int ks = 0; ks < 4; ++ks) {
        short8 a = *(const short8*)&Xs[16 * w + m][ks * 32 + q * 8];
#pragma unroll
        for (int c = 0; c < 8; ++c) {
            short8 bb = *(const short8*)&Ws[c * 16 + m][ks * 32 + q * 8];
            acc[c] = __builtin_amdgcn_mfma_f32_16x16x32_bf16(a, bb, acc[c], 0, 0, 0);
        }
    }

    __syncthreads();   // everyone done reading Xs/Ws

#pragma unroll
    for (int r = 0; r < 4; ++r) {
        int rt = 16 * w + q * 4 + r;            // row in tile
#pragma unroll
        for (int c = 0; c < 8; ++c)
            Xs[rt][c * 16 + m] = f2bf(acc[c][r]);
    }
    __syncthreads();

#pragma unroll
    for (int i = 0; i < 4; ++i) {
        int idx = t + 512 * i;
        int r = idx >> 4, c8 = idx & 15;
        int row = row0 + r;
        if (row < N)
            *(short8*)&h1s[(size_t)row * D1 + c8 * 8] = *(const short8*)&Xs[r][c8 * 8];
    }
}

// ---------------- pass B: per-bucket hist/scan (padded-to-4 degrees)/rp/dinv/esrc
//                  + DESCENDING-degree schedule (order); wave-shfl scans. ---------
__global__ __launch_bounds__(BSZ) void k_binB(
    const int* __restrict__ bcur, const unsigned* __restrict__ packed,
    int2* __restrict__ rp, float* __restrict__ dinv,
    int* __restrict__ esrc, int* __restrict__ order, int N, int CAP)
{
    __shared__ int lh[BSZ];
    __shared__ int lcur[BSZ];
    __shared__ int wsum[BSZ / 64];
    __shared__ int dbin[64];
    __shared__ int dcur[64];

    const int t = threadIdx.x;
    const int s = blockIdx.x << BSH;
    const int n = min(BSZ, N - s);
    const int base = blockIdx.x * CAP;
    const int cnt = min(bcur[blockIdx.x], CAP);

    lh[t] = 0;
    if (t < 64) dbin[t] = 0;
    __syncthreads();
    for (int i = t; i < cnt; i += BSZ)
        atomicAdd(&lh[packed[base + i] & (BSZ - 1)], 1);
    __syncthreads();

    const int deg = lh[t];                   // true degree (in-bucket)
    const int pdeg = (deg + 3) & ~3;         // padded to x4 for int4 index loads

    // exclusive scan of pdeg via wave shfl scans
    int inc = pdeg;
#pragma unroll
    for (int off = 1; off < 64; off <<= 1) {
        int u = __shfl_up(inc, off);
        if ((t & 63) >= off) inc += u;
    }
    if ((t & 63) == 63) wsum[t >> 6] = inc;
    __syncthreads();
    if (t < BSZ / 64) {
        int w = wsum[t];
#pragma unroll
        for (int off = 1; off < BSZ / 64; off <<= 1) {
            int u = __shfl_up(w, off, BSZ / 64);
            if ((t & (BSZ / 64 - 1)) >= off) w += u;
        }
        wsum[t] = w;                               // inclusive wave sums
    }
    __syncthreads();
    int excl = ((t >> 6) ? wsum[(t >> 6) - 1] : 0) + inc - pdeg;

    if (t < n) {
        rp[s + t] = make_int2(base + excl, deg);
        dinv[s + t] = rsqrtf(1.0f + (float)deg);
        atomicAdd(&dbin[63 - min(deg, 63)], 1);    // reversed key -> descending
        for (int k = deg; k < pdeg; ++k) {         // pad slots -> zero-row index
            int p = excl + k;
            if (p < CAP) esrc[base + p] = N;       // clamp (no-op at this fill factor)
        }
    }
    lcur[t] = excl;
    __syncthreads();

    for (int i = t; i < cnt; i += BSZ) {
        unsigned p = packed[base + i];
        int ld = (int)(p & (BSZ - 1));
        int pos = atomicAdd(&lcur[ld], 1);
        if (pos < CAP) esrc[base + pos] = (int)(p >> BSH);
    }

    __syncthreads();
    if (t < 64) {                                  // exactly wave 0
        int dv = dbin[t];
        int dinc = dv;
#pragma unroll
        for (int off = 1; off < 64; off <<= 1) {
            int u = __shfl_up(dinc, off);
            if (t >= off) dinc += u;
        }
        dcur[t] = dinc - dv;
    }
    __syncthreads();
    if (t < n) {
        int b = 63 - min(deg, 63);
        int pos = atomicAdd(&dcur[b], 1);
        order[s + pos] = s + t;
    }
}

#define ACC8F(A, v, d) \
    A[0] += bflo(v.x) * d; A[1] += bfhi(v.x) * d; \
    A[2] += bflo(v.y) * d; A[3] += bfhi(v.y) * d; \
    A[4] += bflo(v.z) * d; A[5] += bfhi(v.z) * d; \
    A[6] += bflo(v.w) * d; A[7] += bfhi(v.w) * d;

// ---------------- fused: agg(layer1) + relu + bias + GEMM2 ------------------------
// r7 structure (quad-masked unroll-8, 1 node per 16-lane group) + per-edge dinv FMA
// (h1s unscaled; dinv is 400KB L2-resident).
__global__ __launch_bounds__(256) void k_agg1_gemm2(
    const int2* __restrict__ rp, const int* __restrict__ esrc,
    const int* __restrict__ order,
    const float* __restrict__ dinv, const unsigned short* __restrict__ h1s,
    const float* __restrict__ b1, const float* __restrict__ W2,
    float* __restrict__ h2s, int N)
{
    int gid = blockIdx.x * 256 + threadIdx.x;
    int grp = gid >> 4;
    if (grp >= N) return;
    int node = order[grp];
    int lane = gid & 15;

    const uint4* h1v = (const uint4*)h1s;   // 16 uint4 per row
    const int4*  ev  = (const int4*)esrc;   // per-node regions are x4-aligned

    float di = dinv[node];
    uint4 u = h1v[(size_t)node * 16 + lane];
    float accA[8], accB[8];
    accA[0] = bflo(u.x) * di; accA[1] = bfhi(u.x) * di;
    accA[2] = bflo(u.y) * di; accA[3] = bfhi(u.y) * di;
    accA[4] = bflo(u.z) * di; accA[5] = bfhi(u.z) * di;
    accA[6] = bflo(u.w) * di; accA[7] = bfhi(u.w) * di;
#pragma unroll
    for (int j = 0; j < 8; ++j) accB[j] = 0.f;

    int2 r = rp[node];
    int beg = r.x;
    int end4 = beg + ((r.y + 3) & ~3);

    for (int e = beg; e < end4; e += 8) {
        int q = e >> 2;
        int4 i0 = ev[q];                     // always valid (real or N-pad)
        int4 i1 = ev[q + 1];                 // in-bounds read; masked if past end4
        bool c1 = (e + 4) < end4;
        int s0 = clampN(i0.x, N), s1 = clampN(i0.y, N);
        int s2 = clampN(i0.z, N), s3 = clampN(i0.w, N);
        int s4 = c1 ? clampN(i1.x, N) : N, s5 = c1 ? clampN(i1.y, N) : N;
        int s6 = c1 ? clampN(i1.z, N) : N, s7 = c1 ? clampN(i1.w, N) : N;
        float d0 = dinv[s0], d1 = dinv[s1], d2 = dinv[s2], d3 = dinv[s3];
        float d4 = dinv[s4], d5 = dinv[s5], d6 = dinv[s6], d7 = dinv[s7];
        uint4 v0 = h1v[(size_t)s0 * 16 + lane];
        uint4 v1 = h1v[(size_t)s1 * 16 + lane];
        uint4 v2 = h1v[(size_t)s2 * 16 + lane];
        uint4 v3 = h1v[(size_t)s3 * 16 + lane];
        uint4 v4 = h1v[(size_t)s4 * 16 + lane];
        uint4 v5 = h1v[(size_t)s5 * 16 + lane];
        uint4 v6 = h1v[(size_t)s6 * 16 + lane];
        uint4 v7 = h1v[(size_t)s7 * 16 + lane];
        ACC8F(accA, v0, d0) ACC8F(accB, v1, d1) ACC8F(accA, v2, d2) ACC8F(accB, v3, d3)
        ACC8F(accA, v4, d4) ACC8F(accB, v5, d5) ACC8F(accA, v6, d6) ACC8F(accB, v7, d7)
    }

    const float4* b1v = (const float4*)b1;
    float4 bbA = b1v[lane * 2 + 0];
    float4 bbB = b1v[lane * 2 + 1];
    float a[8];
    a[0] = fmaxf((accA[0] + accB[0]) * di + bbA.x, 0.f);
    a[1] = fmaxf((accA[1] + accB[1]) * di + bbA.y, 0.f);
    a[2] = fmaxf((accA[2] + accB[2]) * di + bbA.z, 0.f);
    a[3] = fmaxf((accA[3] + accB[3]) * di + bbA.w, 0.f);
    a[4] = fmaxf((accA[4] + accB[4]) * di + bbB.x, 0.f);
    a[5] = fmaxf((accA[5] + accB[5]) * di + bbB.y, 0.f);
    a[6] = fmaxf((accA[6] + accB[6]) * di + bbB.z, 0.f);
    a[7] = fmaxf((accA[7] + accB[7]) * di + bbB.w, 0.f);

    const float4* W2v = (const float4*)W2;
    float p0 = 0.f, p1 = 0.f;
#pragma unroll
    for (int j2 = 0; j2 < 4; ++j2) {
        float4 wv = W2v[lane * 4 + j2];
        p0 += a[j2 * 2] * wv.x + a[j2 * 2 + 1] * wv.z;
        p1 += a[j2 * 2] * wv.y + a[j2 * 2 + 1] * wv.w;
    }

#pragma unroll
    for (int off = 8; off > 0; off >>= 1) {
        p0 += __shfl_xor(p0, off);
        p1 += __shfl_xor(p1, off);
    }
    if (lane == 0) {
        h2s[(size_t)node * 2 + 0] = p0 * di;   // store h2*dinv
        h2s[(size_t)node * 2 + 1] = p1 * di;
    }
}

// ---------------- gather layer 2: out = dinv_i*(h2s_i + sum h2s_src) + b2 -------
__global__ void k_gather2(const int2* __restrict__ rp, const int* __restrict__ esrc,
                          const float* __restrict__ h2s, const float* __restrict__ dinv,
                          const float* __restrict__ b2, float* __restrict__ out, int N)
{
    int i = blockIdx.x * 256 + threadIdx.x;
    if (i >= N) return;
    const float2* h2v = (const float2*)h2s;
    const int4* ev = (const int4*)esrc;
    float2 h = h2v[i];
    float o0a = h.x, o1a = h.y;
    float o0b = 0.f, o1b = 0.f;
    int2 r = rp[i];
    int beg = r.x;
    int end4 = beg + ((r.y + 3) & ~3);
    for (int e = beg; e < end4; e += 16) {
        int q = e >> 2;
        int4 i0 = ev[q];
        int4 i1 = ev[q + 1];
        int4 i2 = ev[q + 2];
        int4 i3 = ev[q + 3];
        bool c1 = (e + 4) < end4, c2 = (e + 8) < end4, c3 = (e + 12) < end4;
        int s0 = clampN(i0.x, N), s1 = clampN(i0.y, N);
        int s2 = clampN(i0.z, N), s3 = clampN(i0.w, N);
        int s4 = c1 ? clampN(i1.x, N) : N, s5 = c1 ? clampN(i1.y, N) : N;
        int s6 = c1 ? clampN(i1.z, N) : N, s7 = c1 ? clampN(i1.w, N) : N;
        int s8 = c2 ? clampN(i2.x, N) : N, s9 = c2 ? clampN(i2.y, N) : N;
        int sa = c2 ? clampN(i2.z, N) : N, sb = c2 ? clampN(i2.w, N) : N;
        int sc = c3 ? clampN(i3.x, N) : N, sd = c3 ? clampN(i3.y, N) : N;
        int se = c3 ? clampN(i3.z, N) : N, sf = c3 ? clampN(i3.w, N) : N;
        float2 v0 = h2v[s0], v1 = h2v[s1], v2 = h2v[s2], v3 = h2v[s3];
        float2 v4 = h2v[s4], v5 = h2v[s5], v6 = h2v[s6], v7 = h2v[s7];
        float2 v8 = h2v[s8], v9 = h2v[s9], va = h2v[sa], vb = h2v[sb];
        float2 vc = h2v[sc], vd = h2v[sd], ve = h2v[se], vf = h2v[sf];
        o0a += v0.x + v2.x + v4.x + v6.x + v8.x + va.x + vc.x + ve.x;
        o1a += v0.y + v2.y + v4.y + v6.y + v8.y + va.y + vc.y + ve.y;
        o0b += v1.x + v3.x + v5.x + v7.x + v9.x + vb.x + vd.x + vf.x;
        o1b += v1.y + v3.y + v5.y + v7.y + v9.y + vb.y + vd.y + vf.y;
    }
    float di = dinv[i];
    ((float2*)out)[i] = make_float2((o0a + o0b) * di + b2[0], (o1a + o1b) * di + b2[1]);
}

extern "C" void kernel_launch(void* const* d_in, const int* in_sizes, int n_in,
                              void* d_out, int out_size, void* d_ws, size_t ws_size,
                              hipStream_t stream)
{
    const float* x  = (const float*)d_in[0];
    const int*   ei = (const int*)d_in[1];
    const float* W1 = (const float*)d_in[2];
    const float* b1 = (const float*)d_in[3];
    const float* W2 = (const float*)d_in[4];
    const float* b2 = (const float*)d_in[5];
    float* out = (float*)d_out;

    const int N = in_sizes[0] / D1;
    const int E = in_sizes[1] / 2;
    const int* src = ei;
    const int* dst = ei + E;

    const int nbuck = (N + BSZ - 1) >> BSH;
    const int avg = (E + nbuck - 1) / nbuck;
    // 2x mean bucket fill + room for per-node x4 padding (<= 3*BSZ), 64-aligned
    const int CAP = (2 * avg + 3 * BSZ + 63) & ~63;

    char* w = (char*)d_ws;
    auto alloc = [&](size_t bytes) -> char* {
        char* r = w;
        w += (bytes + 63) & ~(size_t)63;
        return r;
    };
    unsigned short* h1s = (unsigned short*)alloc((size_t)(N + 1) * D1 * 2); // +pad row
    unsigned short* W1t = (unsigned short*)alloc((size_t)D1 * D1 * 2);
    float* h2s    = (float*)alloc((size_t)(N + 1) * 2 * 4);                 // +pad row
    float* dinv   = (float*)alloc((size_t)(N + 1) * 4);                     // +pad slot
    int2*  rp     = (int2*)alloc((size_t)N * 8);
    int*   order  = (int*)alloc((size_t)N * 4);
    int*   bcur   = (int*)alloc(NBMAX * 4);
    unsigned* packed = (unsigned*)alloc((size_t)nbuck * CAP * 4);
    int*   esrc   = (int*)alloc(((size_t)nbuck * CAP + 256) * 4);           // +overread slack

    const int GA = (E + CHA - 1) / CHA;
    const int GG = (N + BMM - 1) / BMM;

    k_init <<<(D1 * D1 + 255) / 256, 256, 0, stream>>>(W1, W1t, bcur, h1s, h2s, dinv, N);
    k_gemm1_binA<<<GA + GG, 512, 0, stream>>>(x, W1t, h1s, src, dst, bcur, packed,
                                              N, E, nbuck, CAP, GA, GG);
    k_binB <<<nbuck, BSZ, 0, stream>>>(bcur, packed, rp, dinv, esrc, order, N, CAP);

    k_agg1_gemm2<<<(N * 16 + 255) / 256, 256, 0, stream>>>(rp, esrc, order, dinv, h1s, b1, W2, h2s, N);

    k_gather2<<<(N + 255) / 256, 256, 0, stream>>>(rp, esrc, h2s, dinv, b2, out, N);
}